// Round 13
// baseline (38.056 us; speedup 1.0000x reference)
//
#include <hip/hip_runtime.h>
#include <math.h>

#define B_TOT 32768
#define DIM   512
#define NS    100
#define NCOL  101
#define TB    128              // rows per block (8 waves x 16 rows)
#define NBLK  (B_TOT / TB)     // 256 blocks = 1/CU
#define WPITCH 520             // bf16 elems per W row: 1040 B

typedef __attribute__((ext_vector_type(8))) short short8;   // 8 bf16 (4 VGPRs)
typedef __attribute__((ext_vector_type(4))) float f32x4;    // MFMA accumulator
typedef __attribute__((ext_vector_type(4))) float fv4;      // clang vector for NT loads

// fp32 -> bf16 round-to-nearest-even, bit form
static __device__ __forceinline__ short f2bf(float f) {
    unsigned u = __builtin_bit_cast(unsigned, f);
    unsigned r = (u + 0x7FFFu + ((u >> 16) & 1u)) >> 16;
    return (short)r;
}

// Fused: batched W-stage + sampled GEMM (MFMA) + ring-prefetched true-dot gather
// + fused LSE. NT hints: A-stream (read-once) + out (write-once) bypass cache;
// L2/L3 reserved for gather-W reuse and staged W.
__global__ __launch_bounds__(512)
void fused_kernel(const int* __restrict__ label,
                  const float* __restrict__ inputs,
                  const float* __restrict__ weights,
                  const float* __restrict__ biases,
                  const int* __restrict__ sids,
                  const float* __restrict__ tq,
                  const float* __restrict__ sq,
                  float* __restrict__ out,
                  float* __restrict__ lpart)
{
    __shared__ short W_lds[112 * WPITCH];   // 116 KB; rows 100-111 zeroed (pad)
    __shared__ float base_lds[112];         // biases[sid] - log(sq), -inf pad
    __shared__ int   s_sid[NS];
    __shared__ float ls_lds[8];             // per-wave loss partials

    const int t = threadIdx.x;

    if (t < NS) s_sid[t] = sids[t];
    __syncthreads();

    // ---- stage W, phase 1: issue ALL 25 loads (NS*128 = 12800 = 25*512) ----
    fv4 sreg[25];
    #pragma unroll
    for (int q = 0; q < 25; q++) {
        const int idx = t + q * 512;
        sreg[q] = *(const fv4*)(weights + (long)s_sid[idx >> 7] * DIM + (idx & 127) * 4);
    }
    // ---- stage W, phase 2: convert + write (single latency for the whole batch) ----
    #pragma unroll
    for (int q = 0; q < 25; q++) {
        const int idx = t + q * 512;
        *(short4*)&W_lds[(idx >> 7) * WPITCH + (idx & 127) * 4] =
            make_short4(f2bf(sreg[q].x), f2bf(sreg[q].y), f2bf(sreg[q].z), f2bf(sreg[q].w));
    }
    // zero pad rows 100-111 -> pad MFMA results exactly 0
    for (int idx = t; idx < 12 * (WPITCH / 4); idx += 512) {
        const int row = 100 + idx / (WPITCH / 4);
        const int kq  = (idx % (WPITCH / 4)) * 4;
        *(short4*)&W_lds[row * WPITCH + kq] = make_short4(0, 0, 0, 0);
    }
    // base_lds loads issued BEFORE rings so the barrier does not drain the rings
    if (t < 112)
        base_lds[t] = (t < NS) ? biases[s_sid[t]] - logf(sq[t]) : -INFINITY;

    const int wave = t >> 6;
    const int lane = t & 63;
    const int rit  = lane & 15;              // A row within tile / C-D col index
    const int seg  = lane >> 4;              // k-segment (8 k each)
    const long b0  = (long)blockIdx.x * TB;
    const long absRow = b0 + wave * 16 + rit;
    const int lab = label[absRow];
    const float* aptr = inputs  + absRow * DIM + seg * 8;
    const float* wtp  = weights + (long)lab * DIM + seg * 8;

    f32x4 acc_r[7];
    #pragma unroll
    for (int c = 0; c < 7; c++) acc_r[c] = (f32x4){0.f, 0.f, 0.f, 0.f};

    // ---- prefetch rings: gather-W (longest latency, cacheable) depth 8; A (NT) depth 4 ----
    fv4 wr[8][2];
    fv4 ar[4][2];
    #pragma unroll
    for (int p = 0; p < 8; p++) {
        wr[p][0] = *(const fv4*)(wtp + p * 32);
        wr[p][1] = *(const fv4*)(wtp + p * 32 + 4);
    }
    #pragma unroll
    for (int p = 0; p < 4; p++) {
        ar[p][0] = __builtin_nontemporal_load((const fv4*)(aptr + p * 32));
        ar[p][1] = __builtin_nontemporal_load((const fv4*)(aptr + p * 32 + 4));
    }

    // ---- light barrier: LDS visibility only; ring prefetches stay IN FLIGHT ----
    asm volatile("s_waitcnt lgkmcnt(0)" ::: "memory");
    __builtin_amdgcn_s_barrier();

    float t0 = 0.f, t1 = 0.f;
    #pragma unroll
    for (int kc = 0; kc < 16; kc++) {
        const int sa = kc & 3, sw = kc & 7;
        const fv4 a0 = ar[sa][0], a1 = ar[sa][1];
        const fv4 w0 = wr[sw][0], w1 = wr[sw][1];
        if (kc + 8 < 16) {
            wr[sw][0] = *(const fv4*)(wtp + (kc + 8) * 32);
            wr[sw][1] = *(const fv4*)(wtp + (kc + 8) * 32 + 4);
        }
        if (kc + 4 < 16) {
            ar[sa][0] = __builtin_nontemporal_load((const fv4*)(aptr + (kc + 4) * 32));
            ar[sa][1] = __builtin_nontemporal_load((const fv4*)(aptr + (kc + 4) * 32 + 4));
        }

        // true-dot: two independent fp32 chains
        t0 = fmaf(a0.x, w0.x, t0); t0 = fmaf(a0.y, w0.y, t0);
        t0 = fmaf(a0.z, w0.z, t0); t0 = fmaf(a0.w, w0.w, t0);
        t1 = fmaf(a1.x, w1.x, t1); t1 = fmaf(a1.y, w1.y, t1);
        t1 = fmaf(a1.z, w1.z, t1); t1 = fmaf(a1.w, w1.w, t1);

        short8 af;
        af[0] = f2bf(a0.x); af[1] = f2bf(a0.y); af[2] = f2bf(a0.z); af[3] = f2bf(a0.w);
        af[4] = f2bf(a1.x); af[5] = f2bf(a1.y); af[6] = f2bf(a1.z); af[7] = f2bf(a1.w);

        const int wko = kc * 32 + seg * 8;
        #pragma unroll
        for (int c = 0; c < 7; c++) {
            const short8 bf = *(const short8*)&W_lds[(c * 16 + rit) * WPITCH + wko];
            acc_r[c] = __builtin_amdgcn_mfma_f32_16x16x32_bf16(af, bf, acc_r[c], 0, 0, 0);
        }
    }
    float tacc = t0 + t1;

    // ---- true logit: reduce 4 k-segments; every lane gets row (lane&15)'s value ----
    tacc += __shfl_xor(tacc, 16);
    tacc += __shfl_xor(tacc, 32);
    const float tl = tacc + biases[lab] - logf(tq[absRow]);
    if (lane < 16) __builtin_nontemporal_store(tl, &out[absRow * NCOL]);

    // ---- fused per-row LSE + loss + sampled-logit writes ----
    // C/D layout: col = lane&15 (rit), row = (lane>>4)*4 + reg
    const int g = lane >> 4;
    float base_v[7];
    #pragma unroll
    for (int c = 0; c < 7; c++) base_v[c] = base_lds[c * 16 + rit];

    float loss_sum = 0.f;
    #pragma unroll
    for (int i = 0; i < 4; i++) {
        const int r = g * 4 + i;
        const long orow = (b0 + wave * 16 + r) * NCOL;
        const float tlv = __shfl(tl, r);     // lane r holds row r's true logit
        float v[7];
        float m = tlv;
        #pragma unroll
        for (int c = 0; c < 7; c++) {
            v[c] = acc_r[c][i] + base_v[c];  // pad cols: 0 + (-inf) = -inf exactly
            m = fmaxf(m, v[c]);
        }
        #pragma unroll
        for (int off = 1; off < 16; off <<= 1) m = fmaxf(m, __shfl_xor(m, off));
        float s = (rit == 0) ? expf(tlv - m) : 0.f;
        #pragma unroll
        for (int c = 0; c < 7; c++) s += expf(v[c] - m);
        #pragma unroll
        for (int off = 1; off < 16; off <<= 1) s += __shfl_xor(s, off);
        loss_sum += m + logf(s) - tlv;
        #pragma unroll
        for (int c = 0; c < 7; c++) {
            const int col = c * 16 + rit;
            if (col < NS) __builtin_nontemporal_store(v[c], &out[orow + 1 + col]);
        }
    }
    float wl = (rit == 0) ? loss_sum : 0.f;
    wl += __shfl_xor(wl, 16);
    wl += __shfl_xor(wl, 32);
    if (lane == 0) ls_lds[wave] = wl;
    __syncthreads();
    if (t == 0) {
        float bp = 0.f;
        #pragma unroll
        for (int w = 0; w < 8; w++) bp += ls_lds[w];
        lpart[blockIdx.x] = bp;
    }
}

// deterministic single-wave tree reduce of 256 block partials in double -> mean loss
__global__ __launch_bounds__(64)
void reduce_kernel(const float* __restrict__ lpart, float* __restrict__ out_loss)
{
    const int lane = threadIdx.x;
    // fixed pairing: s = sum_{q} lpart[lane + 64q] in index order, then tree
    double s = 0.0;
    #pragma unroll
    for (int q = 0; q < 4; q++) s += (double)lpart[lane + q * 64];
    #pragma unroll
    for (int o = 32; o > 0; o >>= 1) {
        const double other = __shfl_down(s, o);
        s += other;
    }
    if (lane == 0) *out_loss = (float)(s * (1.0 / (double)B_TOT));
}

extern "C" void kernel_launch(void* const* d_in, const int* in_sizes, int n_in,
                              void* d_out, int out_size, void* d_ws, size_t ws_size,
                              hipStream_t stream)
{
    const int*   label   = (const int*)d_in[0];
    const float* inputs  = (const float*)d_in[1];
    const float* weights = (const float*)d_in[2];
    const float* biases  = (const float*)d_in[3];
    const int*   sids    = (const int*)d_in[4];
    const float* tq      = (const float*)d_in[5];
    const float* sq      = (const float*)d_in[6];
    float* out   = (float*)d_out;
    float* lpart = (float*)d_ws;   // 256 floats

    fused_kernel<<<NBLK, 512, 0, stream>>>(label, inputs, weights, biases,
                                           sids, tq, sq, out, lpart);
    reduce_kernel<<<1, 64, 0, stream>>>(lpart, out + (long)B_TOT * NCOL);
}

// Round 14
// 35.284 us; speedup vs baseline: 1.0786x; 1.0786x over previous
//
#include <hip/hip_runtime.h>
#include <math.h>

#define B_TOT 32768
#define DIM   512
#define NS    100
#define NCOL  101
#define TB    128              // rows per block (8 waves x 16 rows)
#define NBLK  (B_TOT / TB)     // 256 blocks = 1/CU
#define WPITCH 520             // bf16 elems per W row: 1040 B

typedef __attribute__((ext_vector_type(8))) short short8;   // 8 bf16 (4 VGPRs)
typedef __attribute__((ext_vector_type(4))) float f32x4;    // MFMA accumulator

// fp32 -> bf16 round-to-nearest-even, bit form
static __device__ __forceinline__ short f2bf(float f) {
    unsigned u = __builtin_bit_cast(unsigned, f);
    unsigned r = (u + 0x7FFFu + ((u >> 16) & 1u)) >> 16;
    return (short)r;
}

// Fused: batched W-stage + sampled GEMM (MFMA) + ring-prefetched true-dot gather
// + fused LSE. Rings: A depth 4, gather-W depth 8; A-refill issued BEFORE W-refill
// so waiting on A@kc does not force early completion of W@kc (in-order vmem queue).
__global__ __launch_bounds__(512)
void fused_kernel(const int* __restrict__ label,
                  const float* __restrict__ inputs,
                  const float* __restrict__ weights,
                  const float* __restrict__ biases,
                  const int* __restrict__ sids,
                  const float* __restrict__ tq,
                  const float* __restrict__ sq,
                  float* __restrict__ out,
                  float* __restrict__ lpart)
{
    __shared__ short W_lds[112 * WPITCH];   // 116 KB; rows 100-111 zeroed (pad)
    __shared__ float base_lds[112];         // biases[sid] - log(sq), -inf pad
    __shared__ int   s_sid[NS];
    __shared__ float ls_lds[8];             // per-wave loss partials

    const int t = threadIdx.x;

    if (t < NS) s_sid[t] = sids[t];
    __syncthreads();

    // ---- stage W, phase 1: issue ALL 25 loads (NS*128 = 12800 = 25*512) ----
    float4 sreg[25];
    #pragma unroll
    for (int q = 0; q < 25; q++) {
        const int idx = t + q * 512;
        sreg[q] = *(const float4*)(weights + (long)s_sid[idx >> 7] * DIM + (idx & 127) * 4);
    }
    // ---- stage W, phase 2: convert + write (single latency for the whole batch) ----
    #pragma unroll
    for (int q = 0; q < 25; q++) {
        const int idx = t + q * 512;
        *(short4*)&W_lds[(idx >> 7) * WPITCH + (idx & 127) * 4] =
            make_short4(f2bf(sreg[q].x), f2bf(sreg[q].y), f2bf(sreg[q].z), f2bf(sreg[q].w));
    }
    // zero pad rows 100-111 -> pad MFMA results exactly 0
    for (int idx = t; idx < 12 * (WPITCH / 4); idx += 512) {
        const int row = 100 + idx / (WPITCH / 4);
        const int kq  = (idx % (WPITCH / 4)) * 4;
        *(short4*)&W_lds[row * WPITCH + kq] = make_short4(0, 0, 0, 0);
    }
    // base_lds loads issued BEFORE rings so the barrier does not drain the rings
    if (t < 112)
        base_lds[t] = (t < NS) ? biases[s_sid[t]] - logf(sq[t]) : -INFINITY;

    const int wave = t >> 6;
    const int lane = t & 63;
    const int rit  = lane & 15;              // A row within tile / C-D col index
    const int seg  = lane >> 4;              // k-segment (8 k each)
    const long b0  = (long)blockIdx.x * TB;
    const long absRow = b0 + wave * 16 + rit;
    const int lab = label[absRow];
    const float* aptr = inputs  + absRow * DIM + seg * 8;
    const float* wtp  = weights + (long)lab * DIM + seg * 8;

    f32x4 acc_r[7];
    #pragma unroll
    for (int c = 0; c < 7; c++) acc_r[c] = (f32x4){0.f, 0.f, 0.f, 0.f};

    // ---- prefetch rings: gather-W (longest latency) depth 8; A depth 4 ----
    float4 wr[8][2];
    float4 ar[4][2];
    #pragma unroll
    for (int p = 0; p < 8; p++) {
        wr[p][0] = *(const float4*)(wtp + p * 32);
        wr[p][1] = *(const float4*)(wtp + p * 32 + 4);
    }
    #pragma unroll
    for (int p = 0; p < 4; p++) {
        ar[p][0] = *(const float4*)(aptr + p * 32);
        ar[p][1] = *(const float4*)(aptr + p * 32 + 4);
    }

    // ---- light barrier: LDS visibility only; ring prefetches stay IN FLIGHT ----
    asm volatile("s_waitcnt lgkmcnt(0)" ::: "memory");
    __builtin_amdgcn_s_barrier();

    float t0 = 0.f, t1 = 0.f;
    #pragma unroll
    for (int kc = 0; kc < 16; kc++) {
        const int sa = kc & 3, sw = kc & 7;
        const float4 a0 = ar[sa][0], a1 = ar[sa][1];
        const float4 w0 = wr[sw][0], w1 = wr[sw][1];
        // A-refill FIRST: waiting on A@kc later must not force W@kc completion
        if (kc + 4 < 16) {
            ar[sa][0] = *(const float4*)(aptr + (kc + 4) * 32);
            ar[sa][1] = *(const float4*)(aptr + (kc + 4) * 32 + 4);
        }
        if (kc + 8 < 16) {
            wr[sw][0] = *(const float4*)(wtp + (kc + 8) * 32);
            wr[sw][1] = *(const float4*)(wtp + (kc + 8) * 32 + 4);
        }

        // true-dot: two independent fp32 chains
        t0 = fmaf(a0.x, w0.x, t0); t0 = fmaf(a0.y, w0.y, t0);
        t0 = fmaf(a0.z, w0.z, t0); t0 = fmaf(a0.w, w0.w, t0);
        t1 = fmaf(a1.x, w1.x, t1); t1 = fmaf(a1.y, w1.y, t1);
        t1 = fmaf(a1.z, w1.z, t1); t1 = fmaf(a1.w, w1.w, t1);

        short8 af;
        af[0] = f2bf(a0.x); af[1] = f2bf(a0.y); af[2] = f2bf(a0.z); af[3] = f2bf(a0.w);
        af[4] = f2bf(a1.x); af[5] = f2bf(a1.y); af[6] = f2bf(a1.z); af[7] = f2bf(a1.w);

        const int wko = kc * 32 + seg * 8;
        #pragma unroll
        for (int c = 0; c < 7; c++) {
            const short8 bf = *(const short8*)&W_lds[(c * 16 + rit) * WPITCH + wko];
            acc_r[c] = __builtin_amdgcn_mfma_f32_16x16x32_bf16(af, bf, acc_r[c], 0, 0, 0);
        }
    }
    float tacc = t0 + t1;

    // ---- true logit: reduce 4 k-segments; every lane gets row (lane&15)'s value ----
    tacc += __shfl_xor(tacc, 16);
    tacc += __shfl_xor(tacc, 32);
    const float tl = tacc + biases[lab] - logf(tq[absRow]);
    if (lane < 16) out[absRow * NCOL] = tl;

    // ---- fused per-row LSE + loss + sampled-logit writes ----
    // C/D layout: col = lane&15 (rit), row = (lane>>4)*4 + reg
    const int g = lane >> 4;
    float base_v[7];
    #pragma unroll
    for (int c = 0; c < 7; c++) base_v[c] = base_lds[c * 16 + rit];

    float loss_sum = 0.f;
    #pragma unroll
    for (int i = 0; i < 4; i++) {
        const int r = g * 4 + i;
        const long orow = (b0 + wave * 16 + r) * NCOL;
        const float tlv = __shfl(tl, r);     // lane r holds row r's true logit
        float v[7];
        float m = tlv;
        #pragma unroll
        for (int c = 0; c < 7; c++) {
            v[c] = acc_r[c][i] + base_v[c];  // pad cols: 0 + (-inf) = -inf exactly
            m = fmaxf(m, v[c]);
        }
        #pragma unroll
        for (int off = 1; off < 16; off <<= 1) m = fmaxf(m, __shfl_xor(m, off));
        float s = (rit == 0) ? expf(tlv - m) : 0.f;
        #pragma unroll
        for (int c = 0; c < 7; c++) s += expf(v[c] - m);
        #pragma unroll
        for (int off = 1; off < 16; off <<= 1) s += __shfl_xor(s, off);
        loss_sum += m + logf(s) - tlv;
        #pragma unroll
        for (int c = 0; c < 7; c++) {
            const int col = c * 16 + rit;
            if (col < NS) out[orow + 1 + col] = v[c];
        }
    }
    float wl = (rit == 0) ? loss_sum : 0.f;
    wl += __shfl_xor(wl, 16);
    wl += __shfl_xor(wl, 32);
    if (lane == 0) ls_lds[wave] = wl;
    __syncthreads();
    if (t == 0) {
        float bp = 0.f;
        #pragma unroll
        for (int w = 0; w < 8; w++) bp += ls_lds[w];
        lpart[blockIdx.x] = bp;
    }
}

// deterministic single-wave tree reduce of 256 block partials in double -> mean loss
__global__ __launch_bounds__(64)
void reduce_kernel(const float* __restrict__ lpart, float* __restrict__ out_loss)
{
    const int lane = threadIdx.x;
    double s = 0.0;
    #pragma unroll
    for (int q = 0; q < 4; q++) s += (double)lpart[lane + q * 64];
    #pragma unroll
    for (int o = 32; o > 0; o >>= 1) {
        const double other = __shfl_down(s, o);
        s += other;
    }
    if (lane == 0) *out_loss = (float)(s * (1.0 / (double)B_TOT));
}

extern "C" void kernel_launch(void* const* d_in, const int* in_sizes, int n_in,
                              void* d_out, int out_size, void* d_ws, size_t ws_size,
                              hipStream_t stream)
{
    const int*   label   = (const int*)d_in[0];
    const float* inputs  = (const float*)d_in[1];
    const float* weights = (const float*)d_in[2];
    const float* biases  = (const float*)d_in[3];
    const int*   sids    = (const int*)d_in[4];
    const float* tq      = (const float*)d_in[5];
    const float* sq      = (const float*)d_in[6];
    float* out   = (float*)d_out;
    float* lpart = (float*)d_ws;   // 256 floats

    fused_kernel<<<NBLK, 512, 0, stream>>>(label, inputs, weights, biases,
                                           sids, tq, sq, out, lpart);
    reduce_kernel<<<1, 64, 0, stream>>>(lpart, out + (long)B_TOT * NCOL);
}